// Round 1
// baseline (3456.410 us; speedup 1.0000x reference)
//
#include <hip/hip_runtime.h>

#define NN 3070      // nodes
#define NF 128       // in features
#define NO 64        // gcn out features
#define NH 50        // hidden
#define NE 49120     // edges
#define NB 128       // batch (= rnn seq len)
#define BCH 32       // batches per chunk
#define NCHUNK 4
#define MCH (BCH * NN)   // 98240 rows per gemm chunk

// ---------------- edge preprocessing ----------------

__global__ __launch_bounds__(256) void zero_kernel(int* __restrict__ p, int n) {
  int i = blockIdx.x * 256 + threadIdx.x;
  if (i < n) p[i] = 0;
}

__global__ __launch_bounds__(256) void mark_kernel(const int* __restrict__ ei, int* __restrict__ mark) {
  int i = blockIdx.x * 256 + threadIdx.x;
  if (i < 2 * NE) mark[ei[i]] = 1;
}

// exclusive prefix scan of n<=3072 ints, single block of 1024 threads, 3 items/thread
__global__ __launch_bounds__(1024) void exscan_kernel(const int* __restrict__ in, int* __restrict__ out,
                                                      int n, int write_total) {
  __shared__ int part[1024];
  int tid = threadIdx.x;
  int base = tid * 3;
  int v0 = (base + 0 < n) ? in[base + 0] : 0;
  int v1 = (base + 1 < n) ? in[base + 1] : 0;
  int v2 = (base + 2 < n) ? in[base + 2] : 0;
  int s = v0 + v1 + v2;
  part[tid] = s;
  __syncthreads();
  for (int off = 1; off < 1024; off <<= 1) {
    int t = (tid >= off) ? part[tid - off] : 0;
    __syncthreads();
    part[tid] += t;
    __syncthreads();
  }
  int run = part[tid] - s;  // exclusive base of this thread's chunk
  if (base + 0 < n) out[base + 0] = run; run += v0;
  if (base + 1 < n) out[base + 1] = run; run += v1;
  if (base + 2 < n) out[base + 2] = run;
  if (write_total && tid == 1023) out[n] = part[1023];
}

__global__ __launch_bounds__(256) void remap_deg_kernel(const int* __restrict__ ei, const float* __restrict__ ew,
    const int* __restrict__ ranks, int* __restrict__ srcr, int* __restrict__ dstr,
    int* __restrict__ degc, float* __restrict__ degw) {
  int e = blockIdx.x * 256 + threadIdx.x;
  if (e >= NE) return;
  int s = ranks[ei[e]];
  int d = ranks[ei[NE + e]];
  srcr[e] = s;
  dstr[e] = d;
  atomicAdd(&degc[d], 1);
  atomicAdd(&degw[d], ew[e]);
}

__global__ __launch_bounds__(256) void dinv_kernel(const float* __restrict__ degw,
    float* __restrict__ dinv, float* __restrict__ selfn) {
  int n = blockIdx.x * 256 + threadIdx.x;
  if (n >= NN) return;
  float dg = degw[n] + 1.0f;  // + self-loop weight 1
  float di = rsqrtf(dg);      // dg >= 1 always
  dinv[n] = di;
  selfn[n] = di * di;         // self-loop message norm
}

__global__ __launch_bounds__(256) void csr_fill_kernel(const float* __restrict__ ew, const int* __restrict__ srcr,
    const int* __restrict__ dstr, const int* __restrict__ rowptr, int* __restrict__ cursor,
    const float* __restrict__ dinv, int* __restrict__ csr_src, float* __restrict__ csr_norm) {
  int e = blockIdx.x * 256 + threadIdx.x;
  if (e >= NE) return;
  int d = dstr[e];
  int s = srcr[e];
  int pos = rowptr[d] + atomicAdd(&cursor[d], 1);
  csr_src[pos] = s;
  csr_norm[pos] = dinv[s] * ew[e] * dinv[d];
}

// ---------------- GEMM: xw = A(M,128) @ W(128,64), fp32 ----------------
// 128-row tile/block, 256 threads, micro-tile 8 rows x 4 cols.
// LDS strides of 68 floats: A-read bank = (4*rg+kk)%32 -> 2-way conflict (free).
__global__ __launch_bounds__(256) void gemm_kernel(const float* __restrict__ A,
    const float* __restrict__ W, float* __restrict__ out, int M) {
  __shared__ float As[128 * 68];
  __shared__ float Ws[64 * 68];
  int tid = threadIdx.x;
  int row0 = blockIdx.x * 128;
  int rg = tid & 15;   // row group: rows rg + 16*i
  int cg = tid >> 4;   // col group: cols cg*4 .. cg*4+3
  float acc[8][4];
#pragma unroll
  for (int i = 0; i < 8; ++i)
#pragma unroll
    for (int j = 0; j < 4; ++j) acc[i][j] = 0.f;

#pragma unroll
  for (int kc = 0; kc < 2; ++kc) {
    // stage A chunk: 128 rows x 64 k
#pragma unroll
    for (int j = 0; j < 8; ++j) {
      int f = tid + 256 * j;       // 0..2047 float4s
      int r = f >> 4, kq = f & 15;
      int grow = row0 + r;
      float4 v = make_float4(0.f, 0.f, 0.f, 0.f);
      if (grow < M) v = *(const float4*)&A[(size_t)grow * NF + kc * 64 + kq * 4];
      *(float4*)&As[r * 68 + kq * 4] = v;
    }
    // stage W chunk: 64 k x 64 cols (k-major, matches global layout)
#pragma unroll
    for (int j = 0; j < 4; ++j) {
      int f = tid + 256 * j;       // 0..1023 float4s
      int kk = f >> 4, q = f & 15;
      float4 v = *(const float4*)&W[(size_t)(kc * 64 + kk) * NO + q * 4];
      *(float4*)&Ws[kk * 68 + q * 4] = v;
    }
    __syncthreads();
#pragma unroll
    for (int kk = 0; kk < 64; kk += 4) {
      float4 a[8];
#pragma unroll
      for (int i = 0; i < 8; ++i) a[i] = *(const float4*)&As[(rg + 16 * i) * 68 + kk];
#pragma unroll
      for (int m = 0; m < 4; ++m) {
        float w0 = Ws[(kk + m) * 68 + cg * 4 + 0];
        float w1 = Ws[(kk + m) * 68 + cg * 4 + 1];
        float w2 = Ws[(kk + m) * 68 + cg * 4 + 2];
        float w3 = Ws[(kk + m) * 68 + cg * 4 + 3];
#pragma unroll
        for (int i = 0; i < 8; ++i) {
          float av = (m == 0) ? a[i].x : (m == 1) ? a[i].y : (m == 2) ? a[i].z : a[i].w;
          acc[i][0] += av * w0;
          acc[i][1] += av * w1;
          acc[i][2] += av * w2;
          acc[i][3] += av * w3;
        }
      }
    }
    __syncthreads();
  }
#pragma unroll
  for (int i = 0; i < 8; ++i) {
    int r = row0 + rg + 16 * i;
    if (r < M) {
      float4 v = make_float4(acc[i][0], acc[i][1], acc[i][2], acc[i][3]);
      *(float4*)&out[(size_t)r * NO + cg * 4] = v;
    }
  }
}

// ---------------- GCN aggregation: atomic-free CSR gather ----------------
// thread = (node_local, f4); 16 nodes x 16 float4-feats per block; grid.y = batch in chunk
__global__ __launch_bounds__(256) void gather_kernel(const float4* __restrict__ xw,
    const int* __restrict__ rowptr, const int* __restrict__ csr_src, const float* __restrict__ csr_norm,
    const float* __restrict__ selfn, const float* __restrict__ bias, float4* __restrict__ outg, int b0) {
  int tid = threadIdx.x;
  int f4 = tid & 15, nl = tid >> 4;
  int n = blockIdx.x * 16 + nl;
  if (n >= NN) return;
  int b = blockIdx.y;
  const float4* xb = xw + (size_t)b * NN * 16;
  float sn = selfn[n];
  float4 v = xb[n * 16 + f4];
  float ax = v.x * sn, ay = v.y * sn, az = v.z * sn, aw = v.w * sn;
  int e0 = rowptr[n], e1 = rowptr[n + 1];
  for (int e = e0; e < e1; ++e) {
    int s = csr_src[e];
    float w = csr_norm[e];
    float4 u = xb[s * 16 + f4];
    ax += w * u.x; ay += w * u.y; az += w * u.z; aw += w * u.w;
  }
  float4 bb = ((const float4*)bias)[f4];
  float4 o = make_float4(ax + bb.x, ay + bb.y, az + bb.z, aw + bb.w);
  outg[((size_t)(b0 + b) * NN + n) * 16 + f4] = o;
}

// ---------------- RNN: per-node-independent recurrence ----------------
// block = 5 nodes x 50 hidden dims (250 active lanes of 256); loops all 128 steps.
// W_ih row (64) + W_hh row (50+2 pad) live in registers; h lives in LDS.
__global__ __launch_bounds__(256, 3) void rnn_kernel(const float* __restrict__ x,
    const float* __restrict__ Wih, const float* __restrict__ Whh,
    const float* __restrict__ bih, const float* __restrict__ bhh,
    const float* __restrict__ h0, float* __restrict__ out) {
  __shared__ float xs[5 * 64];
  __shared__ float hs[5 * 52];
  int tid = threadIdx.x;
  int n0 = blockIdx.x * 5;
  int nl = tid / 50;
  int j = tid - nl * 50;
  bool active = tid < 250;
  float wih[64];
  float whh[52];
  float bj = 0.f;
  if (active) {
#pragma unroll
    for (int q = 0; q < 16; ++q) *(float4*)&wih[4 * q] = *(const float4*)&Wih[j * 64 + 4 * q];
#pragma unroll
    for (int k = 0; k < 50; ++k) whh[k] = Whh[j * 50 + k];
    whh[50] = 0.f; whh[51] = 0.f;
    bj = bih[j] + bhh[j];
  } else {
#pragma unroll
    for (int q = 0; q < 64; ++q) wih[q] = 0.f;
#pragma unroll
    for (int q = 0; q < 52; ++q) whh[q] = 0.f;
  }
  if (tid < 5 * 52) hs[tid] = 0.f;  // zero pad lanes 50/51 per node
  __syncthreads();
  if (active) hs[nl * 52 + j] = h0[n0 * 50 + tid];  // n*50+j == tid for packed layout
  const size_t NX = (size_t)NN * 64;
  const size_t NOUT = (size_t)NN * 50;
  for (int t = 0; t < NB; ++t) {
    if (tid < 80) ((float4*)xs)[tid] = ((const float4*)(x + (size_t)t * NX))[n0 * 16 + tid];
    __syncthreads();  // xs staged; hs writes from t-1 visible
    float hnew = 0.f;
    if (active) {
      float acc = bj;
      const float4* xr = (const float4*)&xs[nl * 64];
#pragma unroll
      for (int q = 0; q < 16; ++q) {
        float4 xv = xr[q];
        acc += xv.x * wih[4 * q] + xv.y * wih[4 * q + 1] + xv.z * wih[4 * q + 2] + xv.w * wih[4 * q + 3];
      }
      const float4* hr = (const float4*)&hs[nl * 52];
#pragma unroll
      for (int q = 0; q < 13; ++q) {
        float4 hv = hr[q];
        acc += hv.x * whh[4 * q] + hv.y * whh[4 * q + 1] + hv.z * whh[4 * q + 2] + hv.w * whh[4 * q + 3];
      }
      hnew = tanhf(acc);
    }
    __syncthreads();  // all hs reads done
    if (active) {
      hs[nl * 52 + j] = hnew;
      out[(size_t)t * NOUT + n0 * 50 + tid] = hnew;  // contiguous 250 floats/block
    }
  }
}

// ---------------- host ----------------

extern "C" void kernel_launch(void* const* d_in, const int* in_sizes, int n_in,
                              void* d_out, int out_size, void* d_ws, size_t ws_size,
                              hipStream_t stream) {
  const float* x_in = (const float*)d_in[0];
  const int* ei     = (const int*)d_in[1];
  const float* ew   = (const float*)d_in[2];
  const float* W    = (const float*)d_in[3];
  const float* bias = (const float*)d_in[4];
  const float* Wih  = (const float*)d_in[5];
  const float* Whh  = (const float*)d_in[6];
  const float* bih  = (const float*)d_in[7];
  const float* bhh  = (const float*)d_in[8];
  const float* h0   = (const float*)d_in[9];
  float* out = (float*)d_out;

  char* ws = (char*)d_ws;
  size_t off = 0;
  auto alloc = [&](size_t bytes) {
    size_t o = off;
    off += (bytes + 255) & ~(size_t)255;
    return o;
  };
  float* xw    = (float*)(ws + alloc((size_t)MCH * NO * 4));          // 25.1 MB (per-chunk)
  float* gcn   = (float*)(ws + alloc((size_t)NB * NN * NO * 4));      // 100.6 MB
  int*   zb    = (int*)(ws + alloc((size_t)4 * NN * 4));              // zeroed each call
  int* mark = zb;
  int* degc = zb + NN;
  float* degw = (float*)(zb + 2 * NN);
  int* cursor = zb + 3 * NN;
  int*   ranks  = (int*)(ws + alloc(NN * 4));
  int*   srcr   = (int*)(ws + alloc(NE * 4));
  int*   dstr   = (int*)(ws + alloc(NE * 4));
  float* dinv   = (float*)(ws + alloc(NN * 4));
  float* selfn  = (float*)(ws + alloc(NN * 4));
  int*   rowptr = (int*)(ws + alloc((NN + 1) * 4));
  int*   csrc   = (int*)(ws + alloc(NE * 4));
  float* cnorm  = (float*)(ws + alloc(NE * 4));

  zero_kernel<<<(4 * NN + 255) / 256, 256, 0, stream>>>(zb, 4 * NN);
  mark_kernel<<<(2 * NE + 255) / 256, 256, 0, stream>>>(ei, mark);
  exscan_kernel<<<1, 1024, 0, stream>>>(mark, ranks, NN, 0);
  remap_deg_kernel<<<(NE + 255) / 256, 256, 0, stream>>>(ei, ew, ranks, srcr, dstr, degc, degw);
  dinv_kernel<<<(NN + 255) / 256, 256, 0, stream>>>(degw, dinv, selfn);
  exscan_kernel<<<1, 1024, 0, stream>>>(degc, rowptr, NN, 1);
  csr_fill_kernel<<<(NE + 255) / 256, 256, 0, stream>>>(ew, srcr, dstr, rowptr, cursor, dinv, csrc, cnorm);

  for (int c = 0; c < NCHUNK; ++c) {
    gemm_kernel<<<(MCH + 127) / 128, 256, 0, stream>>>(
        x_in + (size_t)c * MCH * NF, W, xw, MCH);
    dim3 gg((NN + 15) / 16, BCH);
    gather_kernel<<<gg, 256, 0, stream>>>(
        (const float4*)xw, rowptr, csrc, cnorm, selfn, bias, (float4*)gcn, c * BCH);
  }
  rnn_kernel<<<NN / 5, 256, 0, stream>>>(gcn, Wih, Whh, bih, bhh, h0, out);
}

// Round 2
// 768.844 us; speedup vs baseline: 4.4956x; 4.4956x over previous
//
#include <hip/hip_runtime.h>

#define NN 3070      // nodes
#define NF 128       // in features
#define NO 64        // gcn out features
#define NH 50        // hidden
#define NE 49120     // edges
#define NB 128       // batch (= rnn seq len)
#define BCH 32       // batches per chunk
#define NCHUNK 4
#define MCH (BCH * NN)   // 98240 rows per gemm chunk

// ---------------- edge preprocessing ----------------

__global__ __launch_bounds__(256) void zero_kernel(int* __restrict__ p, int n) {
  int i = blockIdx.x * 256 + threadIdx.x;
  if (i < n) p[i] = 0;
}

__global__ __launch_bounds__(256) void mark_kernel(const int* __restrict__ ei, int* __restrict__ mark) {
  int i = blockIdx.x * 256 + threadIdx.x;
  if (i < 2 * NE) mark[ei[i]] = 1;
}

// exclusive prefix scan of n<=3072 ints, single block of 1024 threads, 3 items/thread
__global__ __launch_bounds__(1024) void exscan_kernel(const int* __restrict__ in, int* __restrict__ out,
                                                      int n, int write_total) {
  __shared__ int part[1024];
  int tid = threadIdx.x;
  int base = tid * 3;
  int v0 = (base + 0 < n) ? in[base + 0] : 0;
  int v1 = (base + 1 < n) ? in[base + 1] : 0;
  int v2 = (base + 2 < n) ? in[base + 2] : 0;
  int s = v0 + v1 + v2;
  part[tid] = s;
  __syncthreads();
  for (int off = 1; off < 1024; off <<= 1) {
    int t = (tid >= off) ? part[tid - off] : 0;
    __syncthreads();
    part[tid] += t;
    __syncthreads();
  }
  int run = part[tid] - s;  // exclusive base of this thread's chunk
  if (base + 0 < n) out[base + 0] = run; run += v0;
  if (base + 1 < n) out[base + 1] = run; run += v1;
  if (base + 2 < n) out[base + 2] = run;
  if (write_total && tid == 1023) out[n] = part[1023];
}

__global__ __launch_bounds__(256) void remap_deg_kernel(const int* __restrict__ ei, const float* __restrict__ ew,
    const int* __restrict__ ranks, int* __restrict__ srcr, int* __restrict__ dstr,
    int* __restrict__ degc, float* __restrict__ degw) {
  int e = blockIdx.x * 256 + threadIdx.x;
  if (e >= NE) return;
  int s = ranks[ei[e]];
  int d = ranks[ei[NE + e]];
  srcr[e] = s;
  dstr[e] = d;
  atomicAdd(&degc[d], 1);
  atomicAdd(&degw[d], ew[e]);
}

__global__ __launch_bounds__(256) void dinv_kernel(const float* __restrict__ degw,
    float* __restrict__ dinv, float* __restrict__ selfn) {
  int n = blockIdx.x * 256 + threadIdx.x;
  if (n >= NN) return;
  float dg = degw[n] + 1.0f;  // + self-loop weight 1
  float di = rsqrtf(dg);      // dg >= 1 always
  dinv[n] = di;
  selfn[n] = di * di;         // self-loop message norm
}

__global__ __launch_bounds__(256) void csr_fill_kernel(const float* __restrict__ ew, const int* __restrict__ srcr,
    const int* __restrict__ dstr, const int* __restrict__ rowptr, int* __restrict__ cursor,
    const float* __restrict__ dinv, int* __restrict__ csr_src, float* __restrict__ csr_norm) {
  int e = blockIdx.x * 256 + threadIdx.x;
  if (e >= NE) return;
  int d = dstr[e];
  int s = srcr[e];
  int pos = rowptr[d] + atomicAdd(&cursor[d], 1);
  csr_src[pos] = s;
  csr_norm[pos] = dinv[s] * ew[e] * dinv[d];
}

// ---------------- GEMM: xw = A(M,128) @ W(128,64), fp32 ----------------
// 128-row tile/block, 256 threads, micro-tile 4 rows x 8 cols (acc=32 VGPRs).
// K chunked by 32 so LDS = 34.8K(A) + 8K(W) = 42K. All LDS access <=2-way (free).
__global__ __launch_bounds__(256) void gemm_kernel(const float* __restrict__ A,
    const float* __restrict__ W, float* __restrict__ out, int M) {
  __shared__ float As[128 * 68];   // [row][k], stride 68 -> A-read bank (4*rg+k)%32, 2-way
  __shared__ float Ws[32 * 64];    // [k][col], broadcast reads
  int tid = threadIdx.x;
  int row0 = blockIdx.x * 128;
  int rg = tid >> 3;        // 0..31 : rows rg + 32*i
  int cg = tid & 7;         // cols cg*8 .. cg*8+7
  int c0 = cg * 8;
  float acc[4][8];
#pragma unroll
  for (int i = 0; i < 4; ++i)
#pragma unroll
    for (int j = 0; j < 8; ++j) acc[i][j] = 0.f;

  for (int kc = 0; kc < 4; ++kc) {
    // stage A chunk: 128 rows x 32 k (4 float4 / thread)
#pragma unroll
    for (int j = 0; j < 4; ++j) {
      int f = tid + 256 * j;        // 0..1023
      int r = f >> 3, kq = f & 7;
      int grow = row0 + r;
      float4 v = make_float4(0.f, 0.f, 0.f, 0.f);
      if (grow < M) v = *(const float4*)&A[(size_t)grow * NF + kc * 32 + kq * 4];
      *(float4*)&As[r * 68 + kq * 4] = v;
    }
    // stage W chunk: 32 k x 64 cols (2 float4 / thread)
#pragma unroll
    for (int j = 0; j < 2; ++j) {
      int f = tid + 256 * j;        // 0..511
      int kk = f >> 4, cq = f & 15;
      *(float4*)&Ws[kk * 64 + cq * 4] = *(const float4*)&W[(size_t)(kc * 32 + kk) * NO + cq * 4];
    }
    __syncthreads();
#pragma unroll 2
    for (int k4 = 0; k4 < 32; k4 += 4) {
      float4 a[4];
#pragma unroll
      for (int i = 0; i < 4; ++i) a[i] = *(const float4*)&As[(rg + 32 * i) * 68 + k4];
#pragma unroll
      for (int m = 0; m < 4; ++m) {
        float4 w0 = *(const float4*)&Ws[(k4 + m) * 64 + c0];
        float4 w1 = *(const float4*)&Ws[(k4 + m) * 64 + c0 + 4];
#pragma unroll
        for (int i = 0; i < 4; ++i) {
          float av = (m == 0) ? a[i].x : (m == 1) ? a[i].y : (m == 2) ? a[i].z : a[i].w;
          acc[i][0] += av * w0.x; acc[i][1] += av * w0.y;
          acc[i][2] += av * w0.z; acc[i][3] += av * w0.w;
          acc[i][4] += av * w1.x; acc[i][5] += av * w1.y;
          acc[i][6] += av * w1.z; acc[i][7] += av * w1.w;
        }
      }
    }
    __syncthreads();
  }
#pragma unroll
  for (int i = 0; i < 4; ++i) {
    int r = row0 + rg + 32 * i;
    if (r < M) {
      *(float4*)&out[(size_t)r * NO + c0] = make_float4(acc[i][0], acc[i][1], acc[i][2], acc[i][3]);
      *(float4*)&out[(size_t)r * NO + c0 + 4] = make_float4(acc[i][4], acc[i][5], acc[i][6], acc[i][7]);
    }
  }
}

// ---------------- GCN aggregation: atomic-free CSR gather ----------------
// thread = (node_local, f4); 16 nodes x 16 float4-feats per block; grid.y = batch in chunk
__global__ __launch_bounds__(256) void gather_kernel(const float4* __restrict__ xw,
    const int* __restrict__ rowptr, const int* __restrict__ csr_src, const float* __restrict__ csr_norm,
    const float* __restrict__ selfn, const float* __restrict__ bias, float4* __restrict__ outg, int b0) {
  int tid = threadIdx.x;
  int f4 = tid & 15, nl = tid >> 4;
  int n = blockIdx.x * 16 + nl;
  if (n >= NN) return;
  int b = blockIdx.y;
  const float4* xb = xw + (size_t)b * NN * 16;
  float sn = selfn[n];
  float4 v = xb[n * 16 + f4];
  float ax = v.x * sn, ay = v.y * sn, az = v.z * sn, aw = v.w * sn;
  int e0 = rowptr[n], e1 = rowptr[n + 1];
  for (int e = e0; e < e1; ++e) {
    int s = csr_src[e];
    float w = csr_norm[e];
    float4 u = xb[s * 16 + f4];
    ax += w * u.x; ay += w * u.y; az += w * u.z; aw += w * u.w;
  }
  float4 bb = ((const float4*)bias)[f4];
  float4 o = make_float4(ax + bb.x, ay + bb.y, az + bb.z, aw + bb.w);
  outg[((size_t)(b0 + b) * NN + n) * 16 + f4] = o;
}

// ---------------- RNN: per-node-independent recurrence ----------------
// block = 5 nodes x 50 hidden dims (250 active lanes of 256); loops all 128 steps.
// W_ih row (64) + W_hh row (50+2 pad) live in registers; h lives in LDS.
// x(t+1) is prefetched into registers while step t computes (hides HBM latency).
__global__ __launch_bounds__(256, 3) void rnn_kernel(const float* __restrict__ x,
    const float* __restrict__ Wih, const float* __restrict__ Whh,
    const float* __restrict__ bih, const float* __restrict__ bhh,
    const float* __restrict__ h0, float* __restrict__ out) {
  __shared__ float xs[5 * 64];
  __shared__ float hs[5 * 52];
  int tid = threadIdx.x;
  int n0 = blockIdx.x * 5;
  int nl = tid / 50;
  int j = tid - nl * 50;
  bool active = tid < 250;
  float wih[64];
  float whh[52];
  float bj = 0.f;
  if (active) {
#pragma unroll
    for (int q = 0; q < 16; ++q) *(float4*)&wih[4 * q] = *(const float4*)&Wih[j * 64 + 4 * q];
#pragma unroll
    for (int k = 0; k < 50; ++k) whh[k] = Whh[j * 50 + k];
    whh[50] = 0.f; whh[51] = 0.f;
    bj = bih[j] + bhh[j];
  } else {
#pragma unroll
    for (int q = 0; q < 64; ++q) wih[q] = 0.f;
#pragma unroll
    for (int q = 0; q < 52; ++q) whh[q] = 0.f;
  }
  if (tid < 5 * 52) hs[tid] = 0.f;  // zero pad lanes 50/51 per node
  __syncthreads();
  if (active) hs[nl * 52 + j] = h0[n0 * 50 + tid];  // n*50+j == tid for packed layout
  const size_t NX = (size_t)NN * 64;
  const size_t NOUT = (size_t)NN * 50;
  float4 xpre = make_float4(0.f, 0.f, 0.f, 0.f);
  if (tid < 80) xpre = ((const float4*)x)[n0 * 16 + tid];
  for (int t = 0; t < NB; ++t) {
    if (tid < 80) ((float4*)xs)[tid] = xpre;
    __syncthreads();  // xs staged; hs writes from t-1 visible
    if (t + 1 < NB && tid < 80)
      xpre = ((const float4*)(x + (size_t)(t + 1) * NX))[n0 * 16 + tid];  // prefetch next step
    float hnew = 0.f;
    if (active) {
      float acc = bj;
      const float4* xr = (const float4*)&xs[nl * 64];
#pragma unroll
      for (int q = 0; q < 16; ++q) {
        float4 xv = xr[q];
        acc += xv.x * wih[4 * q] + xv.y * wih[4 * q + 1] + xv.z * wih[4 * q + 2] + xv.w * wih[4 * q + 3];
      }
      const float4* hr = (const float4*)&hs[nl * 52];
#pragma unroll
      for (int q = 0; q < 13; ++q) {
        float4 hv = hr[q];
        acc += hv.x * whh[4 * q] + hv.y * whh[4 * q + 1] + hv.z * whh[4 * q + 2] + hv.w * whh[4 * q + 3];
      }
      hnew = tanhf(acc);
    }
    __syncthreads();  // all hs reads done
    if (active) {
      hs[nl * 52 + j] = hnew;
      out[(size_t)t * NOUT + n0 * 50 + tid] = hnew;  // contiguous 250 floats/block
    }
  }
}

// ---------------- host ----------------

extern "C" void kernel_launch(void* const* d_in, const int* in_sizes, int n_in,
                              void* d_out, int out_size, void* d_ws, size_t ws_size,
                              hipStream_t stream) {
  const float* x_in = (const float*)d_in[0];
  const int* ei     = (const int*)d_in[1];
  const float* ew   = (const float*)d_in[2];
  const float* W    = (const float*)d_in[3];
  const float* bias = (const float*)d_in[4];
  const float* Wih  = (const float*)d_in[5];
  const float* Whh  = (const float*)d_in[6];
  const float* bih  = (const float*)d_in[7];
  const float* bhh  = (const float*)d_in[8];
  const float* h0   = (const float*)d_in[9];
  float* out = (float*)d_out;

  char* ws = (char*)d_ws;
  size_t off = 0;
  auto alloc = [&](size_t bytes) {
    size_t o = off;
    off += (bytes + 255) & ~(size_t)255;
    return o;
  };
  float* xw    = (float*)(ws + alloc((size_t)MCH * NO * 4));          // 25.1 MB (per-chunk)
  float* gcn   = (float*)(ws + alloc((size_t)NB * NN * NO * 4));      // 100.6 MB
  int*   zb    = (int*)(ws + alloc((size_t)4 * NN * 4));              // zeroed each call
  int* mark = zb;
  int* degc = zb + NN;
  float* degw = (float*)(zb + 2 * NN);
  int* cursor = zb + 3 * NN;
  int*   ranks  = (int*)(ws + alloc(NN * 4));
  int*   srcr   = (int*)(ws + alloc(NE * 4));
  int*   dstr   = (int*)(ws + alloc(NE * 4));
  float* dinv   = (float*)(ws + alloc(NN * 4));
  float* selfn  = (float*)(ws + alloc(NN * 4));
  int*   rowptr = (int*)(ws + alloc((NN + 1) * 4));
  int*   csrc   = (int*)(ws + alloc(NE * 4));
  float* cnorm  = (float*)(ws + alloc(NE * 4));

  zero_kernel<<<(4 * NN + 255) / 256, 256, 0, stream>>>(zb, 4 * NN);
  mark_kernel<<<(2 * NE + 255) / 256, 256, 0, stream>>>(ei, mark);
  exscan_kernel<<<1, 1024, 0, stream>>>(mark, ranks, NN, 0);
  remap_deg_kernel<<<(NE + 255) / 256, 256, 0, stream>>>(ei, ew, ranks, srcr, dstr, degc, degw);
  dinv_kernel<<<(NN + 255) / 256, 256, 0, stream>>>(degw, dinv, selfn);
  exscan_kernel<<<1, 1024, 0, stream>>>(degc, rowptr, NN, 1);
  csr_fill_kernel<<<(NE + 255) / 256, 256, 0, stream>>>(ew, srcr, dstr, rowptr, cursor, dinv, csrc, cnorm);

  for (int c = 0; c < NCHUNK; ++c) {
    gemm_kernel<<<(MCH + 127) / 128, 256, 0, stream>>>(
        x_in + (size_t)c * MCH * NF, W, xw, MCH);
    dim3 gg((NN + 15) / 16, BCH);
    gather_kernel<<<gg, 256, 0, stream>>>(
        (const float4*)xw, rowptr, csrc, cnorm, selfn, bias, (float4*)gcn, c * BCH);
  }
  rnn_kernel<<<NN / 5, 256, 0, stream>>>(gcn, Wih, Whh, bih, bhh, h0, out);
}